// Round 6
// baseline (99.257 us; speedup 1.0000x reference)
//
#include <hip/hip_runtime.h>
#include <hip/hip_bf16.h>

typedef __attribute__((ext_vector_type(8))) short bf16x8;   // 8 bf16 = 4 VGPRs
typedef __attribute__((ext_vector_type(4))) float f32x4;

__device__ __forceinline__ short f2bf(float v) {
    unsigned u = __builtin_bit_cast(unsigned, v);
    u += 0x7fffu + ((u >> 16) & 1u);          // round-to-nearest-even
    return (short)(u >> 16);
}
__device__ __forceinline__ float relu(float v) { return v > 0.f ? v : 0.f; }

// ---------------- prep: build bf16 W-fragments into d_ws ----------------
// Slot (mt=j*8+ot, kt, lane): lane l holds W[o = ot*16 + (l&15)][c = kt*32 + (l>>4)*8 + e].
// Same (group,elem)->k map as the X operand so the HW k-permutation cancels
// (numerically verified R1-R5).
__global__ __launch_bounds__(64)
void prep_wfrag(const float* __restrict__ w, bf16x8* __restrict__ wf) {
    const int mt   = blockIdx.x >> 2;       // 0..39
    const int kt   = blockIdx.x & 3;        // 0..3
    const int lane = threadIdx.x;           // 0..63
    const int j  = mt >> 3;
    const int ot = mt & 7;
    const int o  = ot * 16 + (lane & 15);
    const int c0 = kt * 32 + (lane >> 4) * 8;
    const float* wp = w + ((size_t)o * 128 + c0) * 5 + j;
    bf16x8 f;
    #pragma unroll
    for (int e = 0; e < 8; ++e) f[e] = f2bf(wp[e * 5]);
    wf[(size_t)(mt * 4 + kt) * 64 + lane] = f;
}

// ---------------- main: one block per (n, row-pair), XCD-swizzled ----------------
// Same compute/store structure as R5 (verified). Changes vs R5, both aimed at
// DRAM-page locality of the write stream:
//  (1) bid = (i%8)*128 + i/8: each XCD gets a contiguous h-range, so its CUs
//      concurrently write address-adjacent 256B chunks (h,h+1,.. differ by 256B).
//  (2) plain (L2-cached) stores instead of nontemporal, so the XCD L2 buffers
//      and drains page-coherent bursts.
__global__ __launch_bounds__(512, 4)
void sconv_v6(const float* __restrict__ x, const bf16x8* __restrict__ wf,
              float* __restrict__ out) {
    __shared__ float lds[128 * 64];         // 32 KiB transpose slab

    const int raw = blockIdx.x;             // dispatch index
    const int bid = (raw & 7) * 128 + (raw >> 3);   // XCD-contiguous remap
    const int hp = bid & 31;                // row pair index
    const int n  = bid >> 5;
    const int h0 = hp * 2;

    const int t    = threadIdx.x;
    const int wave = t >> 6;
    const int lane = t & 63;
    const int mh   = wave >> 2;
    const int pt   = wave & 3;
    const int l15  = lane & 15;
    const int lg   = lane >> 4;
    const int pos  = pt * 16 + l15;         // gather position (A row map)

    // ---- gather X fragments for both rows, kept in regs ----
    const float* xb = x + (size_t)n * 128 * 4096 + (size_t)(h0 * 64 + pos);
    bf16x8 xf[2][4];
    #pragma unroll
    for (int r = 0; r < 2; ++r) {
        #pragma unroll
        for (int kt = 0; kt < 4; ++kt) {
            const float* xp = xb + (size_t)r * 64
                            + (size_t)(kt * 32 + lg * 8) * 4096;
            bf16x8 f;
            #pragma unroll
            for (int e = 0; e < 8; ++e) f[e] = f2bf(xp[(size_t)e * 4096]);
            xf[r][kt] = f;
        }
    }

    const int wq  = pt * 4 + lg;            // quad this lane's acc covers
    const int wp0 = pt * 16 + lg * 4;       // first position of that quad

    #pragma unroll
    for (int j = 0; j < 5; ++j) {
        // ---- compute: wf loaded once, used for both rows ----
        f32x4 acc[4][2];
        #pragma unroll
        for (int oi = 0; oi < 4; ++oi) {
            const int ot = mh * 4 + oi;
            const bf16x8* wfp = wf + (size_t)((j * 8 + ot) * 4) * 64 + lane;
            acc[oi][0] = f32x4{0.f, 0.f, 0.f, 0.f};
            acc[oi][1] = f32x4{0.f, 0.f, 0.f, 0.f};
            #pragma unroll
            for (int kt = 0; kt < 4; ++kt) {
                const bf16x8 b = wfp[(size_t)kt * 64];
                acc[oi][0] = __builtin_amdgcn_mfma_f32_16x16x32_bf16(
                    xf[0][kt], b, acc[oi][0], 0, 0, 0);
                acc[oi][1] = __builtin_amdgcn_mfma_f32_16x16x32_bf16(
                    xf[1][kt], b, acc[oi][1], 0, 0, 0);
            }
        }

        // ---- store path per row (R4/R5-proven) ----
        #pragma unroll
        for (int r = 0; r < 2; ++r) {
            const int h = h0 + r;

            // zero-fill the edge column for w-shifted taps
            if (j == 1 && t < 128) lds[t * 64 + ((t & 7) << 2)] = 0.f;
            if (j == 3 && t < 128) lds[t * 64 + ((15 ^ (t & 7)) << 2) + 3] = 0.f;

            #pragma unroll
            for (int oi = 0; oi < 4; ++oi) {
                const int ch = (mh * 4 + oi) * 16 + l15;
                if (j == 0 || j == 2 || j == 4) {
                    f32x4 v;
                    #pragma unroll
                    for (int q = 0; q < 4; ++q) v[q] = relu(acc[oi][r][q]);
                    *reinterpret_cast<f32x4*>(
                        &lds[ch * 64 + ((wq ^ (ch & 7)) << 2)]) = v;
                } else {
                    #pragma unroll
                    for (int q = 0; q < 4; ++q) {
                        const int ws = wp0 + q + (j == 1 ? 1 : -1);
                        if ((unsigned)ws < 64u)
                            lds[ch * 64 + (((ws >> 2) ^ (ch & 7)) << 2) + (ws & 3)]
                                = relu(acc[oi][r][q]);
                    }
                }
            }
            __syncthreads();

            const int  hs = (j == 0) ? ((h + 1) & 63)
                          : (j == 4) ? ((h + 63) & 63) : h;
            const bool zr = (j == 0 && h == 63) || (j == 4 && h == 0);

            #pragma unroll
            for (int i = 0; i < 4; ++i) {
                const int g  = i * 512 + t;
                const int ch = g >> 4;
                const int q  = g & 15;
                f32x4 v = *reinterpret_cast<const f32x4*>(
                    &lds[ch * 64 + ((q ^ (ch & 7)) << 2)]);
                if (zr) v = f32x4{0.f, 0.f, 0.f, 0.f};
                *reinterpret_cast<f32x4*>(
                    out + (((size_t)n * 640 + j * 128 + ch) * 64 + hs) * 64
                        + q * 4) = v;
            }
            if (j < 4 || r < 1) __syncthreads();
        }
    }
}

// ---------------- fallback (R1 kernel) if workspace is too small ----------------
__global__ __launch_bounds__(512, 2)
void sconv_mfma(const float* __restrict__ x, const float* __restrict__ w,
                float* __restrict__ out) {
    __shared__ bf16x8 wfrag[8][4][64];
    const int bid = blockIdx.x;
    const int j   = bid % 5;
    const int hp  = (bid / 5) % 32;
    const int n   = bid / 160;
    const int t = threadIdx.x;
    for (int s = t; s < 2048; s += 512) {
        const int lane = s & 63;
        const int rest = s >> 6;
        const int mt   = rest >> 2;
        const int kt   = rest & 3;
        const int o    = mt * 16 + (lane & 15);
        const int c0   = kt * 32 + (lane >> 4) * 8;
        const float* wp = w + ((size_t)o * 128 + c0) * 5 + j;
        bf16x8 f;
        #pragma unroll
        for (int e = 0; e < 8; ++e) f[e] = f2bf(wp[e * 5]);
        wfrag[mt][kt][lane] = f;
    }
    __syncthreads();
    const int wave = t >> 6;
    const int lane = t & 63;
    const int l15  = lane & 15;
    const int lg   = lane >> 4;
    const int h    = hp * 2 + (wave >> 2);
    const int wcol = (wave & 3) * 16 + l15;
    const int dy[5] = {-1, 0, 0, 0, 1};
    const int dx[5] = { 0,-1, 0, 1, 0};
    const int hi = h + dy[j];
    const int wi = wcol + dx[j];
    const bool valid = ((unsigned)hi < 64u) && ((unsigned)wi < 64u);
    const int hic = hi < 0 ? 0 : (hi > 63 ? 63 : hi);
    const int wic = wi < 0 ? 0 : (wi > 63 ? 63 : wi);
    const float* xb = x + (size_t)n * 128 * 4096 + (size_t)(hic * 64 + wic);
    bf16x8 xf[4];
    #pragma unroll
    for (int kt = 0; kt < 4; ++kt) {
        const int c0 = kt * 32 + lg * 8;
        const float* xp = xb + (size_t)c0 * 4096;
        bf16x8 f;
        #pragma unroll
        for (int e = 0; e < 8; ++e) {
            float v = xp[(size_t)e * 4096];
            f[e] = f2bf(valid ? v : 0.0f);
        }
        xf[kt] = f;
    }
    f32x4 acc[8];
    #pragma unroll
    for (int mt = 0; mt < 8; ++mt) acc[mt] = f32x4{0.f, 0.f, 0.f, 0.f};
    #pragma unroll
    for (int kt = 0; kt < 4; ++kt)
        #pragma unroll
        for (int mt = 0; mt < 8; ++mt)
            acc[mt] = __builtin_amdgcn_mfma_f32_16x16x32_bf16(
                wfrag[mt][kt][lane], xf[kt], acc[mt], 0, 0, 0);
    float* ob = out + ((size_t)n * 640 + (size_t)j * 128) * 4096
                    + (size_t)(h * 64 + wcol);
    #pragma unroll
    for (int mt = 0; mt < 8; ++mt) {
        const int ch = mt * 16 + lg * 4;
        #pragma unroll
        for (int r = 0; r < 4; ++r) {
            float v = acc[mt][r];
            ob[(size_t)(ch + r) * 4096] = v > 0.f ? v : 0.f;
        }
    }
}

extern "C" void kernel_launch(void* const* d_in, const int* in_sizes, int n_in,
                              void* d_out, int out_size, void* d_ws, size_t ws_size,
                              hipStream_t stream) {
    const float* x = (const float*)d_in[0];   // [32,128,64,64] f32
    const float* w = (const float*)d_in[1];   // [128,128,5] f32
    float* out = (float*)d_out;               // [32,640,64,64] f32

    const size_t wf_bytes = (size_t)40 * 4 * 64 * sizeof(bf16x8);  // 160 KiB
    if (ws_size >= wf_bytes) {
        bf16x8* wf = (bf16x8*)d_ws;
        hipLaunchKernelGGL(prep_wfrag, dim3(160), dim3(64), 0, stream, w, wf);
        hipLaunchKernelGGL(sconv_v6, dim3(32 * 32), dim3(512), 0, stream,
                           x, wf, out);
    } else {
        hipLaunchKernelGGL(sconv_mfma, dim3(32 * 32 * 5), dim3(512), 0, stream,
                           x, w, out);
    }
}

// Round 7
// 76.134 us; speedup vs baseline: 1.3037x; 1.3037x over previous
//
#include <hip/hip_runtime.h>
#include <hip/hip_bf16.h>

typedef __attribute__((ext_vector_type(8))) short bf16x8;   // 8 bf16 = 4 VGPRs
typedef __attribute__((ext_vector_type(4))) float f32x4;

__device__ __forceinline__ short f2bf(float v) {
    unsigned u = __builtin_bit_cast(unsigned, v);
    u += 0x7fffu + ((u >> 16) & 1u);          // round-to-nearest-even
    return (short)(u >> 16);
}
__device__ __forceinline__ float relu(float v) { return v > 0.f ? v : 0.f; }

// LDS slab geometry: [64 ch][2 rows][64 w] with +4-float row pad for bank spread.
#define ROWP 68                 // floats per (ch,row) row
#define CHP  136                // floats per ch (2 rows)

// ---------------- prep: build bf16 W-fragments into d_ws ----------------
// Slot (mt=j*8+ot, kt, lane): lane l holds W[o = ot*16 + (l&15)][c = kt*32 + (l>>4)*8 + e].
// Same (group,elem)->k map as the X operand so the HW k-permutation cancels
// (numerically verified R1-R6).
__global__ __launch_bounds__(64)
void prep_wfrag(const float* __restrict__ w, bf16x8* __restrict__ wf) {
    const int mt   = blockIdx.x >> 2;       // 0..39
    const int kt   = blockIdx.x & 3;        // 0..3
    const int lane = threadIdx.x;           // 0..63
    const int j  = mt >> 3;
    const int ot = mt & 7;
    const int o  = ot * 16 + (lane & 15);
    const int c0 = kt * 32 + (lane >> 4) * 8;
    const float* wp = w + ((size_t)o * 128 + c0) * 5 + j;
    bf16x8 f;
    #pragma unroll
    for (int e = 0; e < 8; ++e) f[e] = f2bf(wp[e * 5]);
    wf[(size_t)(mt * 4 + kt) * 64 + lane] = f;
}

// ---------------- main: one block per (n, row-pair) ----------------
// Compute identical to R5 (verified). Store path: per tap, two mh-phases drain
// a [64ch][2row][64w] slab; readback lanes = (2ch x 2row x 16quad) so each NT
// dwordx4 instruction covers 2x 512B-contiguous chunks (row pairs adjacent in
// out). Shifts folded into slab write (w, j=1/3) or store row (h, j=0/4).
__global__ __launch_bounds__(512, 4)
void sconv_v7(const float* __restrict__ x, const bf16x8* __restrict__ wf,
              float* __restrict__ out) {
    __shared__ float lds[64 * CHP];         // ~34 KiB

    const int bid = blockIdx.x;
    const int hp = bid & 31;                // row pair index
    const int n  = bid >> 5;
    const int h0 = hp * 2;

    const int t    = threadIdx.x;
    const int wave = t >> 6;
    const int lane = t & 63;
    const int mh   = wave >> 2;             // channel half (also phase owner)
    const int pt   = wave & 3;              // 16-wide position tile
    const int l15  = lane & 15;
    const int lg   = lane >> 4;
    const int pos  = pt * 16 + l15;         // gather position (A row map)

    // ---- gather X fragments for both rows, kept in regs ----
    const float* xb = x + (size_t)n * 128 * 4096 + (size_t)(h0 * 64 + pos);
    bf16x8 xf[2][4];
    #pragma unroll
    for (int r = 0; r < 2; ++r) {
        #pragma unroll
        for (int kt = 0; kt < 4; ++kt) {
            const float* xp = xb + (size_t)r * 64
                            + (size_t)(kt * 32 + lg * 8) * 4096;
            bf16x8 f;
            #pragma unroll
            for (int e = 0; e < 8; ++e) f[e] = f2bf(xp[(size_t)e * 4096]);
            xf[r][kt] = f;
        }
    }

    const int wq  = pt * 4 + lg;            // quad this lane's acc covers
    const int wp0 = pt * 16 + lg * 4;       // first position of that quad

    #pragma unroll
    for (int j = 0; j < 5; ++j) {
        // ---- compute: wf loaded once, used for both rows (R5-verified) ----
        f32x4 acc[4][2];
        #pragma unroll
        for (int oi = 0; oi < 4; ++oi) {
            const int ot = mh * 4 + oi;
            const bf16x8* wfp = wf + (size_t)((j * 8 + ot) * 4) * 64 + lane;
            acc[oi][0] = f32x4{0.f, 0.f, 0.f, 0.f};
            acc[oi][1] = f32x4{0.f, 0.f, 0.f, 0.f};
            #pragma unroll
            for (int kt = 0; kt < 4; ++kt) {
                const bf16x8 b = wfp[(size_t)kt * 64];
                acc[oi][0] = __builtin_amdgcn_mfma_f32_16x16x32_bf16(
                    xf[0][kt], b, acc[oi][0], 0, 0, 0);
                acc[oi][1] = __builtin_amdgcn_mfma_f32_16x16x32_bf16(
                    xf[1][kt], b, acc[oi][1], 0, 0, 0);
            }
        }

        // ---- two-phase slab drain: p=0 -> ch 0..63, p=1 -> ch 64..127 ----
        #pragma unroll
        for (int p = 0; p < 2; ++p) {
            // edge-column zero-fill for w-shifted taps (disjoint from acc writes)
            if (j == 1 && t < 128) {
                const int cl = t >> 1, r = t & 1;
                lds[cl * CHP + r * ROWP + 0] = 0.f;
            }
            if (j == 3 && t < 128) {
                const int cl = t >> 1, r = t & 1;
                lds[cl * CHP + r * ROWP + 63] = 0.f;
            }
            if (mh == p) {
                #pragma unroll
                for (int oi = 0; oi < 4; ++oi) {
                    const int cl = oi * 16 + l15;   // ch within this half
                    #pragma unroll
                    for (int r = 0; r < 2; ++r) {
                        if (j == 0 || j == 2 || j == 4) {
                            f32x4 v;
                            #pragma unroll
                            for (int q = 0; q < 4; ++q) v[q] = relu(acc[oi][r][q]);
                            *reinterpret_cast<f32x4*>(
                                &lds[cl * CHP + r * ROWP + wq * 4]) = v;
                        } else {
                            #pragma unroll
                            for (int q = 0; q < 4; ++q) {
                                const int ws = wp0 + q + (j == 1 ? 1 : -1);
                                if ((unsigned)ws < 64u)
                                    lds[cl * CHP + r * ROWP + ws]
                                        = relu(acc[oi][r][q]);
                            }
                        }
                    }
                }
            }
            __syncthreads();

            // ---- readback: one instr = 2 ch x 512B-contiguous (2 rows) ----
            #pragma unroll
            for (int i = 0; i < 4; ++i) {
                const int g  = i * 512 + t;
                const int cl = g >> 5;          // 0..63
                const int hr = (g >> 4) & 1;    // row within pair
                const int q  = g & 15;          // quad within row
                f32x4 v = *reinterpret_cast<const f32x4*>(
                    &lds[cl * CHP + hr * ROWP + q * 4]);
                const int h  = h0 + hr;
                const int hs = (j == 0) ? ((h + 1) & 63)
                             : (j == 4) ? ((h + 63) & 63) : h;
                if ((j == 0 && h == 63) || (j == 4 && h == 0))
                    v = f32x4{0.f, 0.f, 0.f, 0.f};
                __builtin_nontemporal_store(
                    v, reinterpret_cast<f32x4*>(
                           out + (((size_t)n * 640 + j * 128 + p * 64 + cl) * 64
                                  + hs) * 64 + q * 4));
            }
            if (j < 4 || p < 1) __syncthreads();
        }
    }
}

// ---------------- fallback (R1 kernel) if workspace is too small ----------------
__global__ __launch_bounds__(512, 2)
void sconv_mfma(const float* __restrict__ x, const float* __restrict__ w,
                float* __restrict__ out) {
    __shared__ bf16x8 wfrag[8][4][64];
    const int bid = blockIdx.x;
    const int j   = bid % 5;
    const int hp  = (bid / 5) % 32;
    const int n   = bid / 160;
    const int t = threadIdx.x;
    for (int s = t; s < 2048; s += 512) {
        const int lane = s & 63;
        const int rest = s >> 6;
        const int mt   = rest >> 2;
        const int kt   = rest & 3;
        const int o    = mt * 16 + (lane & 15);
        const int c0   = kt * 32 + (lane >> 4) * 8;
        const float* wp = w + ((size_t)o * 128 + c0) * 5 + j;
        bf16x8 f;
        #pragma unroll
        for (int e = 0; e < 8; ++e) f[e] = f2bf(wp[e * 5]);
        wfrag[mt][kt][lane] = f;
    }
    __syncthreads();
    const int wave = t >> 6;
    const int lane = t & 63;
    const int l15  = lane & 15;
    const int lg   = lane >> 4;
    const int h    = hp * 2 + (wave >> 2);
    const int wcol = (wave & 3) * 16 + l15;
    const int dy[5] = {-1, 0, 0, 0, 1};
    const int dx[5] = { 0,-1, 0, 1, 0};
    const int hi = h + dy[j];
    const int wi = wcol + dx[j];
    const bool valid = ((unsigned)hi < 64u) && ((unsigned)wi < 64u);
    const int hic = hi < 0 ? 0 : (hi > 63 ? 63 : hi);
    const int wic = wi < 0 ? 0 : (wi > 63 ? 63 : wi);
    const float* xb = x + (size_t)n * 128 * 4096 + (size_t)(hic * 64 + wic);
    bf16x8 xf[4];
    #pragma unroll
    for (int kt = 0; kt < 4; ++kt) {
        const int c0 = kt * 32 + lg * 8;
        const float* xp = xb + (size_t)c0 * 4096;
        bf16x8 f;
        #pragma unroll
        for (int e = 0; e < 8; ++e) {
            float v = xp[(size_t)e * 4096];
            f[e] = f2bf(valid ? v : 0.0f);
        }
        xf[kt] = f;
    }
    f32x4 acc[8];
    #pragma unroll
    for (int mt = 0; mt < 8; ++mt) acc[mt] = f32x4{0.f, 0.f, 0.f, 0.f};
    #pragma unroll
    for (int kt = 0; kt < 4; ++kt)
        #pragma unroll
        for (int mt = 0; mt < 8; ++mt)
            acc[mt] = __builtin_amdgcn_mfma_f32_16x16x32_bf16(
                wfrag[mt][kt][lane], xf[kt], acc[mt], 0, 0, 0);
    float* ob = out + ((size_t)n * 640 + (size_t)j * 128) * 4096
                    + (size_t)(h * 64 + wcol);
    #pragma unroll
    for (int mt = 0; mt < 8; ++mt) {
        const int ch = mt * 16 + lg * 4;
        #pragma unroll
        for (int r = 0; r < 4; ++r) {
            float v = acc[mt][r];
            ob[(size_t)(ch + r) * 4096] = v > 0.f ? v : 0.f;
        }
    }
}

extern "C" void kernel_launch(void* const* d_in, const int* in_sizes, int n_in,
                              void* d_out, int out_size, void* d_ws, size_t ws_size,
                              hipStream_t stream) {
    const float* x = (const float*)d_in[0];   // [32,128,64,64] f32
    const float* w = (const float*)d_in[1];   // [128,128,5] f32
    float* out = (float*)d_out;               // [32,640,64,64] f32

    const size_t wf_bytes = (size_t)40 * 4 * 64 * sizeof(bf16x8);  // 160 KiB
    if (ws_size >= wf_bytes) {
        bf16x8* wf = (bf16x8*)d_ws;
        hipLaunchKernelGGL(prep_wfrag, dim3(160), dim3(64), 0, stream, w, wf);
        hipLaunchKernelGGL(sconv_v7, dim3(32 * 32), dim3(512), 0, stream,
                           x, wf, out);
    } else {
        hipLaunchKernelGGL(sconv_mfma, dim3(32 * 32 * 5), dim3(512), 0, stream,
                           x, w, out);
    }
}